// Round 15
// baseline (210.777 us; speedup 1.0000x reference)
//
#include <hip/hip_runtime.h>
#include <hip/hip_bf16.h>

// GCN: x=emb[ids]; x1=relu(GCNConv(x,W1,b1)); y=Ahat@x1; out[g]=b2+(mean_g y)@W2
//
// Structure (R15): zero global scattered atomics; fp8 feature-sliced gather.
//  - E edges partitioned into 512 dst-buckets (8 per graph, graph-aligned).
//    Key = {dstLocalGraph(12)|src(17)}.
//  - conv1 per-bucket in LDS (bins CL[node][type]), dense x1 compute;
//    self-loop pool contribution added in fp32 directly (R14).
//  - z = dinv*x1 in FP8 e4m3, stored SLICE-MAJOR: z4[f4][node][16 ushorts],
//    f4 = feature-pair group (pairs p=f4*16+u, feats (p, p+64)).
//  - R15: conv2g feature-sliced by XCD pair: fs=(b%8)>>1 -> per-XCD z
//    working set 3.2 MB (L2-resident; kills the 8x z re-fetch ~100 MB seen
//    when src is uniform-random). partsKey read 4x instead (cheaper).
//    int4 vectorized edge loads in p1/part; dinvA dense array; gb2+t1 merged.

#define DDIM 128
#define GMAX 64
#define BPG  8                 // buckets per graph
#define NBK  (GMAX * BPG)      // 512 buckets
#define NPB  2048              // partition blocks
#define SLICES 32              // conv2 item-slices per graph
#define MAXGN 2048             // max nodes per graph (mean 1563, +12 sigma)
typedef unsigned int uint;
typedef unsigned short ushort;
typedef float v2f __attribute__((ext_vector_type(2)));

// Setup: block 0 -> gBound[65] + bkBound[513]; blocks 1..17 -> t1 = emb@W1 rows.
__global__ void __launch_bounds__(256) k_setup(
        const int* __restrict__ batch, int N,
        int* __restrict__ gBound, int* __restrict__ bkBound,
        const float* __restrict__ emb, const float* __restrict__ W1,
        float* __restrict__ t1) {
    int t = threadIdx.x, b = blockIdx.x;
    if (b == 0) {
        __shared__ int gB[GMAX + 1];
        if (t <= GMAX) {
            int key = t, lo = 0, hi = N;
            while (lo < hi) {
                int mid = (lo + hi) >> 1;
                if (batch[mid] < key) lo = mid + 1; else hi = mid;
            }
            gB[t] = lo;
            gBound[t] = lo;
        }
        __syncthreads();
        for (int bk = t; bk <= NBK; bk += 256) {
            int v;
            if (bk == NBK) v = gB[GMAX];
            else {
                int g = bk >> 3, s = bk & 7;
                int A = gB[g], L = gB[g + 1] - A;
                v = A + (int)((long long)L * s / BPG);
            }
            bkBound[bk] = v;
        }
    } else {
        int row = b - 1;                 // 0..16
        if (t < DDIM) {
            float acc = 0.f;
            for (int k = 0; k < DDIM; k++) acc += emb[row * DDIM + k] * W1[k * DDIM + t];
            t1[row * DDIM + t] = acc;
        }
    }
}

__device__ __forceinline__ int bksearch(const int* bkB, int idx) {
    int lo = 0, hi = NBK - 1;
#pragma unroll
    for (int it = 0; it < 9; it++) {           // 2^9 = 512
        int mid = (lo + hi + 1) >> 1;
        if (bkB[mid] <= idx) lo = mid; else hi = mid - 1;
    }
    return lo;
}

// per-block item range, rounded to 4 elems so int4 loads stay 16B-aligned
__device__ __forceinline__ void blockRange(int E, int b, int& lo, int& hi) {
    int per = ((E + NPB - 1) / NPB + 3) & ~3;
    lo = b * per;
    hi = lo + per; if (hi > E) hi = E;
    if (lo > E) lo = E;
}

// Pass 1: per-block bucket histogram over E edges (int4 loads).
__global__ void __launch_bounds__(256) k_p1(
        const int* __restrict__ dst, const int* __restrict__ bkBound,
        int* __restrict__ blockHist, int E) {
    __shared__ int h[NBK];
    __shared__ int bkB[NBK + 1];
    int t = threadIdx.x;
    for (int k = t; k < NBK; k += 256) h[k] = 0;
    for (int k = t; k <= NBK; k += 256) bkB[k] = bkBound[k];
    __syncthreads();
    int lo, hi; blockRange(E, blockIdx.x, lo, hi);
    for (int cb = lo; cb < hi; cb += 1024) {
        if (cb + 1024 <= hi) {                     // full chunk: int4
            int4 d4 = *(const int4*)(dst + cb + t * 4);
            atomicAdd(&h[bksearch(bkB, d4.x)], 1);
            atomicAdd(&h[bksearch(bkB, d4.y)], 1);
            atomicAdd(&h[bksearch(bkB, d4.z)], 1);
            atomicAdd(&h[bksearch(bkB, d4.w)], 1);
        } else {
#pragma unroll
            for (int q = 0; q < 4; q++) {
                int item = cb + q * 256 + t;
                if (item < hi) atomicAdd(&h[bksearch(bkB, dst[item])], 1);
            }
        }
    }
    __syncthreads();
    for (int k = t; k < NBK; k += 256) blockHist[blockIdx.x * NBK + k] = h[k];
}

// Per-bucket exclusive scan over NPB block histograms.
__global__ void __launch_bounds__(256) k_scanG(
        const int* __restrict__ blockHist, int* __restrict__ localBase,
        int* __restrict__ tot) {
    __shared__ int sm[256];
    int g = blockIdx.x, t = threadIdx.x;
    const int PER = NPB / 256;     // 8
    int v[PER], loc[PER];
    int run = 0;
#pragma unroll
    for (int q = 0; q < PER; q++) {
        v[q] = blockHist[(t * PER + q) * NBK + g];
        loc[q] = run;
        run += v[q];
    }
    sm[t] = run; __syncthreads();
    for (int off = 1; off < 256; off <<= 1) {
        int a = (t >= off) ? sm[t - off] : 0;
        __syncthreads();
        sm[t] += a; __syncthreads();
    }
    int excl = sm[t] - run;
#pragma unroll
    for (int q = 0; q < PER; q++)
        localBase[(t * PER + q) * NBK + g] = excl + loc[q];
    if (t == 255) tot[g] = sm[255];
}

// bkStart[513] from tot[512]
__global__ void __launch_bounds__(256) k_scanT(
        const int* __restrict__ tot, int* __restrict__ bkStart) {
    __shared__ int sm[256];
    int t = threadIdx.x;
    int v0 = tot[2 * t], v1 = tot[2 * t + 1];
    int run = v0 + v1;
    sm[t] = run; __syncthreads();
    for (int off = 1; off < 256; off <<= 1) {
        int a = (t >= off) ? sm[t - off] : 0;
        __syncthreads();
        sm[t] += a; __syncthreads();
    }
    int excl = sm[t] - run;
    bkStart[2 * t] = excl;
    bkStart[2 * t + 1] = excl + v0;
    if (t == 255) bkStart[NBK] = sm[255];
}

// Pass 2: scatter packed keys {dstLocalGraph(12)|src(17)} bucket-major.
__global__ void __launch_bounds__(256) k_part(
        const int* __restrict__ src, const int* __restrict__ dst,
        const int* __restrict__ bkBound, const int* __restrict__ localBase,
        const int* __restrict__ bkStart, uint* __restrict__ partsKey, int E) {
    __shared__ int rk[NBK];
    __shared__ int runOff[NBK];
    __shared__ int base[NBK];
    __shared__ int bkB[NBK + 1];
    __shared__ uint sbuf[1024];
    __shared__ ushort sb2[1024];
    __shared__ int sms[256];
    int t = threadIdx.x, b = blockIdx.x;
    for (int k = t; k < NBK; k += 256) base[k] = bkStart[k] + localBase[b * NBK + k];
    for (int k = t; k <= NBK; k += 256) bkB[k] = bkBound[k];
    int lo, hi; blockRange(E, b, lo, hi);
    for (int cb = lo; cb < hi; cb += 1024) {
        int cnt = hi - cb; if (cnt > 1024) cnt = 1024;
        for (int k = t; k < NBK; k += 256) rk[k] = 0;
        __syncthreads();
        uint key_[4]; int bk_[4], r_[4]; bool v_[4];
        if (cb + 1024 <= hi) {                     // full chunk: int4 loads
            int4 s4 = *(const int4*)(src + cb + t * 4);
            int4 d4 = *(const int4*)(dst + cb + t * 4);
            int ss[4] = {s4.x, s4.y, s4.z, s4.w};
            int dd[4] = {d4.x, d4.y, d4.z, d4.w};
#pragma unroll
            for (int q = 0; q < 4; q++) {
                v_[q] = true;
                int bk = bksearch(bkB, dd[q]);
                bk_[q] = bk;
                int dLG = dd[q] - bkB[(bk >> 3) << 3];
                key_[q] = ((uint)dLG << 17) | (uint)ss[q];
            }
        } else {
#pragma unroll
            for (int q = 0; q < 4; q++) {
                int item = cb + q * 256 + t;
                v_[q] = item < hi;
                key_[q] = 0; bk_[q] = 0;
                if (v_[q]) {
                    int s = src[item], d = dst[item];
                    int bk = bksearch(bkB, d);
                    bk_[q] = bk;
                    int dLG = d - bkB[(bk >> 3) << 3];
                    key_[q] = ((uint)dLG << 17) | (uint)s;
                }
            }
        }
#pragma unroll
        for (int q = 0; q < 4; q++)
            if (v_[q]) r_[q] = atomicAdd(&rk[bk_[q]], 1);
        __syncthreads();
        {   // pair-scan rk[512] -> runOff (exclusive)
            int v0 = rk[2 * t], v1 = rk[2 * t + 1];
            int run = v0 + v1;
            sms[t] = run; __syncthreads();
            for (int off = 1; off < 256; off <<= 1) {
                int a = (t >= off) ? sms[t - off] : 0;
                __syncthreads();
                sms[t] += a; __syncthreads();
            }
            int excl = sms[t] - run;
            runOff[2 * t] = excl;
            runOff[2 * t + 1] = excl + v0;
        }
        __syncthreads();
#pragma unroll
        for (int q = 0; q < 4; q++)                // LDS sort by bucket
            if (v_[q]) {
                int p = runOff[bk_[q]] + r_[q];
                sbuf[p] = key_[q];
                sb2[p] = (ushort)bk_[q];
            }
        __syncthreads();
#pragma unroll
        for (int q = 0; q < 4; q++) {              // coalesced run write-out
            int p = q * 256 + t;
            if (p < cnt) {
                int bk = sb2[p];
                partsKey[base[bk] + (p - runOff[bk])] = sbuf[p];
            }
        }
        __syncthreads();
        for (int k = t; k < NBK; k += 256) base[k] += rk[k];
        __syncthreads();
    }
}

// Per-bucket: count bucket-local dst -> nd (+ dense dinvA).
__global__ void __launch_bounds__(256) k_cnt2(
        const uint* __restrict__ partsKey, const int* __restrict__ bkBound,
        const int* __restrict__ bkStart, const int* __restrict__ ids,
        float2* __restrict__ nd, float* __restrict__ dinvA) {
    __shared__ int cnt[256];
    int b = blockIdx.x, t = threadIdx.x;
    cnt[t] = 0;
    __syncthreads();
    int nodeLo = bkBound[b];
    int gOff = nodeLo - bkBound[(b >> 3) << 3];  // bucket offset within graph
    int lo = bkStart[b], hi = bkStart[b + 1];
    for (int idx = lo + t; idx < hi; idx += 256) {
        uint key = partsKey[idx];
        int dL = (int)((key >> 17) & 0xFFF) - gOff;
        atomicAdd(&cnt[dL], 1);
    }
    __syncthreads();
    int nn = bkBound[b + 1] - nodeLo;
    if (t < nn) {
        int i = nodeLo + t;
        float dinv = rsqrtf((float)(cnt[t] + 1));
        nd[i] = make_float2(dinv, __int_as_float(ids[i]));
        dinvA[i] = dinv;
    }
}

// Per-bucket conv1: LDS bins CL[node][type] (8-wide batched gathers), dense
// x1; z = dinv*x1 in FP8 e4m3 slice-major; self-loop pool (fp32) -> poolY.
__global__ void __launch_bounds__(256) k_x1b(
        const uint* __restrict__ partsKey, const int* __restrict__ bkBound,
        const int* __restrict__ bkStart, const float2* __restrict__ nd,
        const float* __restrict__ t1, const float* __restrict__ b1,
        ushort* __restrict__ z4, float* __restrict__ poolY, int N) {
    __shared__ float t1s[17 * DDIM];    // 8.7 KB
    __shared__ float CL[256 * 17];      // 17.4 KB
    __shared__ float2 ndL[256];
    __shared__ float bL[DDIM];
    __shared__ float redS[4][DDIM];     // self-pool reduce
    int b = blockIdx.x, t = threadIdx.x;
    int nodeLo = bkBound[b], nn = bkBound[b + 1] - nodeLo;
    int gOff = nodeLo - bkBound[(b >> 3) << 3];
    for (int k = t; k < 17 * DDIM; k += 256) t1s[k] = t1[k];
    for (int k = t; k < 256 * 17; k += 256) CL[k] = 0.f;
    if (t < DDIM) bL[t] = b1[t];
    if (t < nn) ndL[t] = nd[nodeLo + t];
    __syncthreads();
    int lo = bkStart[b], hi = bkStart[b + 1];
    for (int cb = lo; cb < hi; cb += 2048) {
        uint key_[8]; bool v_[8];
#pragma unroll
        for (int q = 0; q < 8; q++) {
            int idx = cb + q * 256 + t;
            v_[q] = idx < hi;
            key_[q] = v_[q] ? partsKey[idx] : 0u;
        }
#pragma unroll
        for (int q = 0; q < 8; q++) {
            if (v_[q]) {
                uint key = key_[q];
                int s = key & 0x1FFFF;
                int dL = (int)((key >> 17) & 0xFFF) - gOff;
                float2 ns = nd[s];              // random 8B gather (8 in flight)
                atomicAdd(&CL[dL * 17 + __float_as_int(ns.y)], ns.x);
            }
        }
    }
    __syncthreads();
    int lane = t & 63, wave = t >> 6;
    int f4 = lane >> 4, u = lane & 15;          // pair p = lane = f4*16+u... 
    // NOTE: pair p handled by lane == feats (lane, lane+64); slice = lane>>4.
    float sx = 0.f, sy = 0.f;                   // self-loop pool partials
    for (int n = wave; n < nn; n += 4) {
        float dinv = ndL[n].x;
        int ti = __float_as_int(ndL[n].y);
        float ax = dinv * t1s[ti * DDIM + lane];
        float ay = dinv * t1s[ti * DDIM + 64 + lane];
#pragma unroll
        for (int tt = 0; tt < 17; tt++) {
            float c = CL[n * 17 + tt];
            ax += c * t1s[tt * DDIM + lane];
            ay += c * t1s[tt * DDIM + 64 + lane];
        }
        float vx = bL[lane]      + dinv * ax;
        float vy = bL[64 + lane] + dinv * ay;
        vx = vx > 0.f ? vx : 0.f;
        vy = vy > 0.f ? vy : 0.f;
        // z = dinv * x1, fp8 e4m3 packed pair, slice-major store
        int pk = __builtin_amdgcn_cvt_pk_fp8_f32(dinv * vx, dinv * vy, 0, false);
        z4[(size_t)f4 * N * 16 + (size_t)(nodeLo + n) * 16 + u] = (ushort)(pk & 0xFFFF);
        float d2 = dinv * dinv;
        sx += d2 * vx;                           // self loop, fp32 path
        sy += d2 * vy;
    }
    redS[wave][lane] = sx;
    redS[wave][64 + lane] = sy;
    __syncthreads();
    if (wave == 0) {
        int g = b >> 3;
        float vx = redS[0][lane] + redS[1][lane] + redS[2][lane] + redS[3][lane];
        float vy = redS[0][64 + lane] + redS[1][64 + lane]
                 + redS[2][64 + lane] + redS[3][64 + lane];
        atomicAdd(&poolY[g * DDIM + lane], vx);
        atomicAdd(&poolY[g * DDIM + 64 + lane], vy);
    }
}

// conv2+pool, feature-sliced: block handles (graph g, item-slice sl, feature
// slice fs). fs = (b%8)>>1 pins each z4 slice to one XCD pair (3.2 MB,
// L2-resident). Wave-load = 4 items x 16 feat-pairs. Branchless sentinel.
__global__ void __launch_bounds__(256) k_conv2g(
        const uint* __restrict__ partsKey, const int* __restrict__ bkStart,
        const int* __restrict__ gBound, const float* __restrict__ dinvA,
        const ushort* __restrict__ z4, float* __restrict__ poolY, int N) {
    __shared__ float dinvG[MAXGN];      // 8 KB
    __shared__ uint  mk[4][64];
    __shared__ float redx[4][64];
    __shared__ float redy[4][64];
    int t = threadIdx.x, lane = t & 63, wave = t >> 6;
    int b = blockIdx.x;
    int fs = (b & 7) >> 1;                       // feature slice = XCD pair
    int idx2 = (b >> 3) + (b & 1) * 1024;        // [0,2048) per fs
    int g = idx2 >> 5, sl = idx2 & 31;
    int nLo = gBound[g], nn = gBound[g + 1] - nLo;
    for (int k = t; k < nn; k += 256) dinvG[k] = dinvA[nLo + k];
    if (t == 0) dinvG[MAXGN - 1] = 0.f;          // sentinel weight
    __syncthreads();
    int a = bkStart[g * BPG], bnd = bkStart[(g + 1) * BPG];
    long long len = bnd - a;
    int s0 = a + (int)(len * sl / SLICES);
    int s1 = a + (int)(len * (sl + 1) / SLICES);
    const uint SENT = (uint)(MAXGN - 1) << 17;   // dLG=2047, src=0
    const ushort* zs = z4 + (size_t)fs * N * 16;
    int isub = lane >> 4, u = lane & 15;
    float ax = 0.f, ay = 0.f;
    for (int cb = s0 + wave * 64; cb < s1; cb += 4 * 64) {
        int idx = cb + lane;
        mk[wave][lane] = (idx < s1) ? partsKey[idx] : SENT;
#pragma unroll
        for (int st = 0; st < 16; st++) {
            uint key = mk[wave][st * 4 + isub];
            uint v = (uint)zs[(size_t)(key & 0x1FFFF) * 16 + u];
            float w = dinvG[(key >> 17) & 0xFFF];
            v2f f = __builtin_amdgcn_cvt_pk_f32_fp8((int)v, false);
            ax += w * f.x;
            ay += w * f.y;
        }
    }
    redx[wave][lane] = ax;
    redy[wave][lane] = ay;
    __syncthreads();
    if (t < 16) {
        float sx = 0.f, sy = 0.f;
#pragma unroll
        for (int w = 0; w < 4; w++)
#pragma unroll
            for (int is = 0; is < 4; is++) {
                sx += redx[w][is * 16 + t];
                sy += redy[w][is * 16 + t];
            }
        atomicAdd(&poolY[g * DDIM + fs * 16 + t], sx);          // feat p
        atomicAdd(&poolY[g * DDIM + 64 + fs * 16 + t], sy);     // feat p+64
    }
}

// out[g] = b2 + (poolY[g]/cnt[g]) @ W2 ; cnt from gBound
__global__ void __launch_bounds__(128) k_out(
        const float* __restrict__ poolY, const int* __restrict__ gBound,
        const float* __restrict__ W2, const float* __restrict__ b2,
        float* __restrict__ out) {
    __shared__ float py[DDIM];
    int g = blockIdx.x, f = threadIdx.x;
    py[f] = poolY[g * DDIM + f];
    __syncthreads();
    float acc = 0.f;
    for (int k = 0; k < DDIM; k++) acc += py[k] * W2[k * DDIM + f];
    int c = gBound[g + 1] - gBound[g];
    out[g * DDIM + f] = (c > 0) ? (b2[f] + acc / (float)c) : 0.f;
}

extern "C" void kernel_launch(void* const* d_in, const int* in_sizes, int n_in,
                              void* d_out, int out_size, void* d_ws, size_t ws_size,
                              hipStream_t stream) {
    const int* node_ids = (const int*)d_in[0];
    const int* edge_index = (const int*)d_in[1];
    const int* batch = (const int*)d_in[2];
    const float* emb = (const float*)d_in[4];
    const float* W1 = (const float*)d_in[5];
    const float* b1 = (const float*)d_in[6];
    const float* W2 = (const float*)d_in[7];
    const float* b2 = (const float*)d_in[8];
    float* out = (float*)d_out;

    const int N = in_sizes[0];
    const int E = in_sizes[1] / 2;
    const int* src = edge_index;
    const int* dst = edge_index + E;

    char* ws = (char*)d_ws;
    size_t off = 0;
    auto carve = [&](size_t bytes) { char* p = ws + off; off = (off + bytes + 255) & ~size_t(255); return p; };
    ushort* z4        = (ushort*)carve((size_t)N * 64 * 2);    // fp8x2 slice-major
    uint*   partsKey  = (uint*)carve((size_t)E * 4);           // dLG|src
    float2* nd        = (float2*)carve((size_t)N * 8);
    float*  dinvA     = (float*)carve((size_t)N * 4);
    int*    blockHist = (int*)carve((size_t)NPB * NBK * 4);    // 4.2 MB
    int*    localBase = (int*)carve((size_t)NPB * NBK * 4);    // 4.2 MB
    int*    tot       = (int*)carve(NBK * 4);
    int*    bkStart   = (int*)carve((NBK + 1) * 4);
    int*    gBound    = (int*)carve((GMAX + 1) * 4);
    int*    bkBound   = (int*)carve((NBK + 1) * 4);
    float*  t1        = (float*)carve(17 * DDIM * 4);
    float*  poolY     = (float*)carve((size_t)GMAX * DDIM * 4);

    hipMemsetAsync(poolY, 0, (size_t)GMAX * DDIM * 4, stream);

    k_setup<<<18, 256, 0, stream>>>(batch, N, gBound, bkBound, emb, W1, t1);
    k_p1<<<NPB, 256, 0, stream>>>(dst, bkBound, blockHist, E);
    k_scanG<<<NBK, 256, 0, stream>>>(blockHist, localBase, tot);
    k_scanT<<<1, 256, 0, stream>>>(tot, bkStart);
    k_part<<<NPB, 256, 0, stream>>>(src, dst, bkBound, localBase, bkStart,
                                    partsKey, E);
    k_cnt2<<<NBK, 256, 0, stream>>>(partsKey, bkBound, bkStart, node_ids, nd, dinvA);
    k_x1b<<<NBK, 256, 0, stream>>>(partsKey, bkBound, bkStart, nd, t1, b1,
                                   z4, poolY, N);
    k_conv2g<<<GMAX * SLICES * 4, 256, 0, stream>>>(partsKey, bkStart, gBound,
                                                    dinvA, z4, poolY, N);
    k_out<<<GMAX, 128, 0, stream>>>(poolY, gBound, W2, b2, out);
}

// Round 16
// 198.742 us; speedup vs baseline: 1.0606x; 1.0606x over previous
//
#include <hip/hip_runtime.h>
#include <hip/hip_bf16.h>

// GCN: x=emb[ids]; x1=relu(GCNConv(x,W1,b1)); y=Ahat@x1; out[g]=b2+(mean_g y)@W2
//
// Structure (R16 = R14 conv2g + R15 keepers): zero global scattered atomics.
//  - E edges partitioned into 512 dst-buckets (8 per graph, graph-aligned).
//    Key = {dstLocalGraph(12)|src(17)}.
//  - conv1 per-bucket in LDS (bins CL[node][type]), dense x1 compute;
//    self-loop pool contribution in fp32 directly.
//  - z[s] = dinv_s * x1[s] in FP8 e4m3, ROW-major 128 B/row (R15's
//    feature-sliced layout regressed: 32 B segments + 4x partsKey reads
//    outweighed the z re-fetch savings).
//  - conv2+pool: per-(graph,slice) register accumulation, 16-wide gathers,
//    branchless sentinel, dinv_d from dense dinvA via LDS table.
//  - Keepers from R15: int4 edge loads (p1/part), merged setup, dinvA.

#define DDIM 128
#define GMAX 64
#define BPG  8                 // buckets per graph
#define NBK  (GMAX * BPG)      // 512 buckets
#define NPB  2048              // partition blocks
#define SLICES 32              // conv2 item-slices per graph
#define MAXGN 2048             // max nodes per graph (mean 1563, +12 sigma)
typedef unsigned int uint;
typedef unsigned short ushort;
typedef float v2f __attribute__((ext_vector_type(2)));

// Setup: block 0 -> gBound[65] + bkBound[513]; blocks 1..17 -> t1 = emb@W1 rows.
__global__ void __launch_bounds__(256) k_setup(
        const int* __restrict__ batch, int N,
        int* __restrict__ gBound, int* __restrict__ bkBound,
        const float* __restrict__ emb, const float* __restrict__ W1,
        float* __restrict__ t1) {
    int t = threadIdx.x, b = blockIdx.x;
    if (b == 0) {
        __shared__ int gB[GMAX + 1];
        if (t <= GMAX) {
            int key = t, lo = 0, hi = N;
            while (lo < hi) {
                int mid = (lo + hi) >> 1;
                if (batch[mid] < key) lo = mid + 1; else hi = mid;
            }
            gB[t] = lo;
            gBound[t] = lo;
        }
        __syncthreads();
        for (int bk = t; bk <= NBK; bk += 256) {
            int v;
            if (bk == NBK) v = gB[GMAX];
            else {
                int g = bk >> 3, s = bk & 7;
                int A = gB[g], L = gB[g + 1] - A;
                v = A + (int)((long long)L * s / BPG);
            }
            bkBound[bk] = v;
        }
    } else {
        int row = b - 1;                 // 0..16
        if (t < DDIM) {
            float acc = 0.f;
            for (int k = 0; k < DDIM; k++) acc += emb[row * DDIM + k] * W1[k * DDIM + t];
            t1[row * DDIM + t] = acc;
        }
    }
}

__device__ __forceinline__ int bksearch(const int* bkB, int idx) {
    int lo = 0, hi = NBK - 1;
#pragma unroll
    for (int it = 0; it < 9; it++) {           // 2^9 = 512
        int mid = (lo + hi + 1) >> 1;
        if (bkB[mid] <= idx) lo = mid; else hi = mid - 1;
    }
    return lo;
}

// per-block item range, rounded to 4 elems so int4 loads stay 16B-aligned
__device__ __forceinline__ void blockRange(int E, int b, int& lo, int& hi) {
    int per = ((E + NPB - 1) / NPB + 3) & ~3;
    lo = b * per;
    hi = lo + per; if (hi > E) hi = E;
    if (lo > E) lo = E;
}

// Pass 1: per-block bucket histogram over E edges (int4 loads).
__global__ void __launch_bounds__(256) k_p1(
        const int* __restrict__ dst, const int* __restrict__ bkBound,
        int* __restrict__ blockHist, int E) {
    __shared__ int h[NBK];
    __shared__ int bkB[NBK + 1];
    int t = threadIdx.x;
    for (int k = t; k < NBK; k += 256) h[k] = 0;
    for (int k = t; k <= NBK; k += 256) bkB[k] = bkBound[k];
    __syncthreads();
    int lo, hi; blockRange(E, blockIdx.x, lo, hi);
    for (int cb = lo; cb < hi; cb += 1024) {
        if (cb + 1024 <= hi) {                     // full chunk: int4
            int4 d4 = *(const int4*)(dst + cb + t * 4);
            atomicAdd(&h[bksearch(bkB, d4.x)], 1);
            atomicAdd(&h[bksearch(bkB, d4.y)], 1);
            atomicAdd(&h[bksearch(bkB, d4.z)], 1);
            atomicAdd(&h[bksearch(bkB, d4.w)], 1);
        } else {
#pragma unroll
            for (int q = 0; q < 4; q++) {
                int item = cb + q * 256 + t;
                if (item < hi) atomicAdd(&h[bksearch(bkB, dst[item])], 1);
            }
        }
    }
    __syncthreads();
    for (int k = t; k < NBK; k += 256) blockHist[blockIdx.x * NBK + k] = h[k];
}

// Per-bucket exclusive scan over NPB block histograms.
__global__ void __launch_bounds__(256) k_scanG(
        const int* __restrict__ blockHist, int* __restrict__ localBase,
        int* __restrict__ tot) {
    __shared__ int sm[256];
    int g = blockIdx.x, t = threadIdx.x;
    const int PER = NPB / 256;     // 8
    int v[PER], loc[PER];
    int run = 0;
#pragma unroll
    for (int q = 0; q < PER; q++) {
        v[q] = blockHist[(t * PER + q) * NBK + g];
        loc[q] = run;
        run += v[q];
    }
    sm[t] = run; __syncthreads();
    for (int off = 1; off < 256; off <<= 1) {
        int a = (t >= off) ? sm[t - off] : 0;
        __syncthreads();
        sm[t] += a; __syncthreads();
    }
    int excl = sm[t] - run;
#pragma unroll
    for (int q = 0; q < PER; q++)
        localBase[(t * PER + q) * NBK + g] = excl + loc[q];
    if (t == 255) tot[g] = sm[255];
}

// bkStart[513] from tot[512]
__global__ void __launch_bounds__(256) k_scanT(
        const int* __restrict__ tot, int* __restrict__ bkStart) {
    __shared__ int sm[256];
    int t = threadIdx.x;
    int v0 = tot[2 * t], v1 = tot[2 * t + 1];
    int run = v0 + v1;
    sm[t] = run; __syncthreads();
    for (int off = 1; off < 256; off <<= 1) {
        int a = (t >= off) ? sm[t - off] : 0;
        __syncthreads();
        sm[t] += a; __syncthreads();
    }
    int excl = sm[t] - run;
    bkStart[2 * t] = excl;
    bkStart[2 * t + 1] = excl + v0;
    if (t == 255) bkStart[NBK] = sm[255];
}

// Pass 2: scatter packed keys {dstLocalGraph(12)|src(17)} bucket-major.
__global__ void __launch_bounds__(256) k_part(
        const int* __restrict__ src, const int* __restrict__ dst,
        const int* __restrict__ bkBound, const int* __restrict__ localBase,
        const int* __restrict__ bkStart, uint* __restrict__ partsKey, int E) {
    __shared__ int rk[NBK];
    __shared__ int runOff[NBK];
    __shared__ int base[NBK];
    __shared__ int bkB[NBK + 1];
    __shared__ uint sbuf[1024];
    __shared__ ushort sb2[1024];
    __shared__ int sms[256];
    int t = threadIdx.x, b = blockIdx.x;
    for (int k = t; k < NBK; k += 256) base[k] = bkStart[k] + localBase[b * NBK + k];
    for (int k = t; k <= NBK; k += 256) bkB[k] = bkBound[k];
    int lo, hi; blockRange(E, b, lo, hi);
    for (int cb = lo; cb < hi; cb += 1024) {
        int cnt = hi - cb; if (cnt > 1024) cnt = 1024;
        for (int k = t; k < NBK; k += 256) rk[k] = 0;
        __syncthreads();
        uint key_[4]; int bk_[4], r_[4]; bool v_[4];
        if (cb + 1024 <= hi) {                     // full chunk: int4 loads
            int4 s4 = *(const int4*)(src + cb + t * 4);
            int4 d4 = *(const int4*)(dst + cb + t * 4);
            int ss[4] = {s4.x, s4.y, s4.z, s4.w};
            int dd[4] = {d4.x, d4.y, d4.z, d4.w};
#pragma unroll
            for (int q = 0; q < 4; q++) {
                v_[q] = true;
                int bk = bksearch(bkB, dd[q]);
                bk_[q] = bk;
                int dLG = dd[q] - bkB[(bk >> 3) << 3];
                key_[q] = ((uint)dLG << 17) | (uint)ss[q];
            }
        } else {
#pragma unroll
            for (int q = 0; q < 4; q++) {
                int item = cb + q * 256 + t;
                v_[q] = item < hi;
                key_[q] = 0; bk_[q] = 0;
                if (v_[q]) {
                    int s = src[item], d = dst[item];
                    int bk = bksearch(bkB, d);
                    bk_[q] = bk;
                    int dLG = d - bkB[(bk >> 3) << 3];
                    key_[q] = ((uint)dLG << 17) | (uint)s;
                }
            }
        }
#pragma unroll
        for (int q = 0; q < 4; q++)
            if (v_[q]) r_[q] = atomicAdd(&rk[bk_[q]], 1);
        __syncthreads();
        {   // pair-scan rk[512] -> runOff (exclusive)
            int v0 = rk[2 * t], v1 = rk[2 * t + 1];
            int run = v0 + v1;
            sms[t] = run; __syncthreads();
            for (int off = 1; off < 256; off <<= 1) {
                int a = (t >= off) ? sms[t - off] : 0;
                __syncthreads();
                sms[t] += a; __syncthreads();
            }
            int excl = sms[t] - run;
            runOff[2 * t] = excl;
            runOff[2 * t + 1] = excl + v0;
        }
        __syncthreads();
#pragma unroll
        for (int q = 0; q < 4; q++)                // LDS sort by bucket
            if (v_[q]) {
                int p = runOff[bk_[q]] + r_[q];
                sbuf[p] = key_[q];
                sb2[p] = (ushort)bk_[q];
            }
        __syncthreads();
#pragma unroll
        for (int q = 0; q < 4; q++) {              // coalesced run write-out
            int p = q * 256 + t;
            if (p < cnt) {
                int bk = sb2[p];
                partsKey[base[bk] + (p - runOff[bk])] = sbuf[p];
            }
        }
        __syncthreads();
        for (int k = t; k < NBK; k += 256) base[k] += rk[k];
        __syncthreads();
    }
}

// Per-bucket: count bucket-local dst -> nd (+ dense dinvA).
__global__ void __launch_bounds__(256) k_cnt2(
        const uint* __restrict__ partsKey, const int* __restrict__ bkBound,
        const int* __restrict__ bkStart, const int* __restrict__ ids,
        float2* __restrict__ nd, float* __restrict__ dinvA) {
    __shared__ int cnt[256];
    int b = blockIdx.x, t = threadIdx.x;
    cnt[t] = 0;
    __syncthreads();
    int nodeLo = bkBound[b];
    int gOff = nodeLo - bkBound[(b >> 3) << 3];  // bucket offset within graph
    int lo = bkStart[b], hi = bkStart[b + 1];
    for (int idx = lo + t; idx < hi; idx += 256) {
        uint key = partsKey[idx];
        int dL = (int)((key >> 17) & 0xFFF) - gOff;
        atomicAdd(&cnt[dL], 1);
    }
    __syncthreads();
    int nn = bkBound[b + 1] - nodeLo;
    if (t < nn) {
        int i = nodeLo + t;
        float dinv = rsqrtf((float)(cnt[t] + 1));
        nd[i] = make_float2(dinv, __int_as_float(ids[i]));
        dinvA[i] = dinv;
    }
}

// Per-bucket conv1: LDS bins CL[node][type] (8-wide batched gathers), dense
// x1; z = dinv*x1 in FP8 e4m3 row-major; self-loop pool (fp32) -> poolY.
__global__ void __launch_bounds__(256) k_x1b(
        const uint* __restrict__ partsKey, const int* __restrict__ bkBound,
        const int* __restrict__ bkStart, const float2* __restrict__ nd,
        const float* __restrict__ t1, const float* __restrict__ b1,
        ushort* __restrict__ z, float* __restrict__ poolY) {
    __shared__ float t1s[17 * DDIM];    // 8.7 KB
    __shared__ float CL[256 * 17];      // 17.4 KB
    __shared__ float2 ndL[256];
    __shared__ float bL[DDIM];
    __shared__ float redS[4][DDIM];     // self-pool reduce
    int b = blockIdx.x, t = threadIdx.x;
    int nodeLo = bkBound[b], nn = bkBound[b + 1] - nodeLo;
    int gOff = nodeLo - bkBound[(b >> 3) << 3];
    for (int k = t; k < 17 * DDIM; k += 256) t1s[k] = t1[k];
    for (int k = t; k < 256 * 17; k += 256) CL[k] = 0.f;
    if (t < DDIM) bL[t] = b1[t];
    if (t < nn) ndL[t] = nd[nodeLo + t];
    __syncthreads();
    int lo = bkStart[b], hi = bkStart[b + 1];
    for (int cb = lo; cb < hi; cb += 2048) {
        uint key_[8]; bool v_[8];
#pragma unroll
        for (int q = 0; q < 8; q++) {
            int idx = cb + q * 256 + t;
            v_[q] = idx < hi;
            key_[q] = v_[q] ? partsKey[idx] : 0u;
        }
#pragma unroll
        for (int q = 0; q < 8; q++) {
            if (v_[q]) {
                uint key = key_[q];
                int s = key & 0x1FFFF;
                int dL = (int)((key >> 17) & 0xFFF) - gOff;
                float2 ns = nd[s];              // random 8B gather (8 in flight)
                atomicAdd(&CL[dL * 17 + __float_as_int(ns.y)], ns.x);
            }
        }
    }
    __syncthreads();
    int lane = t & 63, wave = t >> 6;
    float sx = 0.f, sy = 0.f;                   // self-loop pool partials
    for (int n = wave; n < nn; n += 4) {
        float dinv = ndL[n].x;
        int ti = __float_as_int(ndL[n].y);
        float ax = dinv * t1s[ti * DDIM + lane];
        float ay = dinv * t1s[ti * DDIM + 64 + lane];
#pragma unroll
        for (int tt = 0; tt < 17; tt++) {
            float c = CL[n * 17 + tt];
            ax += c * t1s[tt * DDIM + lane];
            ay += c * t1s[tt * DDIM + 64 + lane];
        }
        float vx = bL[lane]      + dinv * ax;
        float vy = bL[64 + lane] + dinv * ay;
        vx = vx > 0.f ? vx : 0.f;
        vy = vy > 0.f ? vy : 0.f;
        // z = dinv * x1, fp8 e4m3 packed pair, row-major store
        int pk = __builtin_amdgcn_cvt_pk_fp8_f32(dinv * vx, dinv * vy, 0, false);
        z[(size_t)(nodeLo + n) * 64 + lane] = (ushort)(pk & 0xFFFF);
        float d2 = dinv * dinv;
        sx += d2 * vx;                           // self loop, fp32 path
        sy += d2 * vy;
    }
    redS[wave][lane] = sx;
    redS[wave][64 + lane] = sy;
    __syncthreads();
    if (wave == 0) {
        int g = b >> 3;
        float vx = redS[0][lane] + redS[1][lane] + redS[2][lane] + redS[3][lane];
        float vy = redS[0][64 + lane] + redS[1][64 + lane]
                 + redS[2][64 + lane] + redS[3][64 + lane];
        atomicAdd(&poolY[g * DDIM + lane], vx);
        atomicAdd(&poolY[g * DDIM + 64 + lane], vy);
    }
}

// conv2+pool: block owns one (graph, slice). Weight = dinv_d from LDS table;
// rows fp8 z (128 B). Branchless: pad sentinel dLG=2047, dinvG[2047]=0.
__global__ void __launch_bounds__(256) k_conv2g(
        const uint* __restrict__ partsKey, const int* __restrict__ bkStart,
        const int* __restrict__ gBound, const float* __restrict__ dinvA,
        const ushort* __restrict__ z, float* __restrict__ poolY) {
    __shared__ float dinvG[MAXGN];      // 8 KB
    __shared__ uint  mk[4][64];
    __shared__ float red[4][DDIM];
    int t = threadIdx.x, lane = t & 63, wave = t >> 6;
    int b = blockIdx.x;
    int j = b >> 3;
    int g = (b & 7) * 8 + (j >> 5);
    int sl = j & 31;
    int nLo = gBound[g], nn = gBound[g + 1] - nLo;
    for (int k = t; k < nn; k += 256) dinvG[k] = dinvA[nLo + k];
    if (t == 0) dinvG[MAXGN - 1] = 0.f;          // sentinel weight
    __syncthreads();
    int a = bkStart[g * BPG], bnd = bkStart[(g + 1) * BPG];
    long long len = bnd - a;
    int s0 = a + (int)(len * sl / SLICES);
    int s1 = a + (int)(len * (sl + 1) / SLICES);
    const uint SENT = (uint)(MAXGN - 1) << 17;   // dLG=2047, src=0
    float ax = 0.f, ay = 0.f;
    for (int cb = s0 + wave * 64; cb < s1; cb += 4 * 64) {
        int idx = cb + lane;
        mk[wave][lane] = (idx < s1) ? partsKey[idx] : SENT;
#pragma unroll
        for (int jj = 0; jj < 64; jj += 16) {
            uint kk[16]; uint vv[16];
#pragma unroll
            for (int k = 0; k < 16; k++) kk[k] = mk[wave][jj + k];
#pragma unroll
            for (int k = 0; k < 16; k++)
                vv[k] = (uint)z[(size_t)(kk[k] & 0x1FFFF) * 64 + lane];
#pragma unroll
            for (int k = 0; k < 16; k++) {
                float w = dinvG[(kk[k] >> 17) & 0xFFF];  // LDS broadcast
                v2f f = __builtin_amdgcn_cvt_pk_f32_fp8((int)vv[k], false);
                ax += w * f.x;
                ay += w * f.y;
            }
        }
    }
    red[wave][lane] = ax;
    red[wave][64 + lane] = ay;
    __syncthreads();
    if (wave == 0) {
        float vx = red[0][lane] + red[1][lane] + red[2][lane] + red[3][lane];
        float vy = red[0][64 + lane] + red[1][64 + lane] + red[2][64 + lane] + red[3][64 + lane];
        atomicAdd(&poolY[g * DDIM + lane], vx);
        atomicAdd(&poolY[g * DDIM + 64 + lane], vy);
    }
}

// out[g] = b2 + (poolY[g]/cnt[g]) @ W2 ; cnt from gBound
__global__ void __launch_bounds__(128) k_out(
        const float* __restrict__ poolY, const int* __restrict__ gBound,
        const float* __restrict__ W2, const float* __restrict__ b2,
        float* __restrict__ out) {
    __shared__ float py[DDIM];
    int g = blockIdx.x, f = threadIdx.x;
    py[f] = poolY[g * DDIM + f];
    __syncthreads();
    float acc = 0.f;
    for (int k = 0; k < DDIM; k++) acc += py[k] * W2[k * DDIM + f];
    int c = gBound[g + 1] - gBound[g];
    out[g * DDIM + f] = (c > 0) ? (b2[f] + acc / (float)c) : 0.f;
}

extern "C" void kernel_launch(void* const* d_in, const int* in_sizes, int n_in,
                              void* d_out, int out_size, void* d_ws, size_t ws_size,
                              hipStream_t stream) {
    const int* node_ids = (const int*)d_in[0];
    const int* edge_index = (const int*)d_in[1];
    const int* batch = (const int*)d_in[2];
    const float* emb = (const float*)d_in[4];
    const float* W1 = (const float*)d_in[5];
    const float* b1 = (const float*)d_in[6];
    const float* W2 = (const float*)d_in[7];
    const float* b2 = (const float*)d_in[8];
    float* out = (float*)d_out;

    const int N = in_sizes[0];
    const int E = in_sizes[1] / 2;
    const int* src = edge_index;
    const int* dst = edge_index + E;

    char* ws = (char*)d_ws;
    size_t off = 0;
    auto carve = [&](size_t bytes) { char* p = ws + off; off = (off + bytes + 255) & ~size_t(255); return p; };
    ushort* z         = (ushort*)carve((size_t)N * 64 * 2);    // fp8x2, 128 B/row
    uint*   partsKey  = (uint*)carve((size_t)E * 4);           // dLG|src
    float2* nd        = (float2*)carve((size_t)N * 8);
    float*  dinvA     = (float*)carve((size_t)N * 4);
    int*    blockHist = (int*)carve((size_t)NPB * NBK * 4);    // 4.2 MB
    int*    localBase = (int*)carve((size_t)NPB * NBK * 4);    // 4.2 MB
    int*    tot       = (int*)carve(NBK * 4);
    int*    bkStart   = (int*)carve((NBK + 1) * 4);
    int*    gBound    = (int*)carve((GMAX + 1) * 4);
    int*    bkBound   = (int*)carve((NBK + 1) * 4);
    float*  t1        = (float*)carve(17 * DDIM * 4);
    float*  poolY     = (float*)carve((size_t)GMAX * DDIM * 4);

    hipMemsetAsync(poolY, 0, (size_t)GMAX * DDIM * 4, stream);

    k_setup<<<18, 256, 0, stream>>>(batch, N, gBound, bkBound, emb, W1, t1);
    k_p1<<<NPB, 256, 0, stream>>>(dst, bkBound, blockHist, E);
    k_scanG<<<NBK, 256, 0, stream>>>(blockHist, localBase, tot);
    k_scanT<<<1, 256, 0, stream>>>(tot, bkStart);
    k_part<<<NPB, 256, 0, stream>>>(src, dst, bkBound, localBase, bkStart,
                                    partsKey, E);
    k_cnt2<<<NBK, 256, 0, stream>>>(partsKey, bkBound, bkStart, node_ids, nd, dinvA);
    k_x1b<<<NBK, 256, 0, stream>>>(partsKey, bkBound, bkStart, nd, t1, b1, z, poolY);
    k_conv2g<<<GMAX * SLICES, 256, 0, stream>>>(partsKey, bkStart, gBound,
                                                dinvA, z, poolY);
    k_out<<<GMAX, 128, 0, stream>>>(poolY, gBound, W2, b2, out);
}